// Round 11
// baseline (360.240 us; speedup 1.0000x reference)
//
#include <hip/hip_runtime.h>
#include <math.h>

#define EMB_D 64
#define N_EMB_K 1024
#define HW 4096        // 64*64
#define CHW 262144     // 64*4096
#define NPTS 65536     // 16*64*64
#define Q_OFF 1
#define PERP_OFF 4194305
#define ENC_OFF 4194306
#define FRAG_OFF 4096   // floats: bf16-hi W fragments at ws+16KB (128 KB)

// ws layout (floats): [0..1023] c[k]=0.5||W_k||^2 ; [1024..2047] hist(uint) ;
// [2048] loss ; [4096..36863] bf16-hi B-frags (128 KB, chunk-lane order)

typedef __attribute__((ext_vector_type(8))) short short8;   // MFMA A/B frag (4 VGPRs)
typedef __attribute__((ext_vector_type(4))) float float4v;  // MFMA C/D frag
typedef __attribute__((ext_vector_type(2))) float f2;
typedef __attribute__((ext_vector_type(4))) float f4;

union S8 { short8 v; unsigned short u[8]; };

__device__ __forceinline__ unsigned short f2bf_rne(float f) {
    unsigned u = __builtin_bit_cast(unsigned, f);
    unsigned r = u + 0x7FFFu + ((u >> 16) & 1u);
    return (unsigned short)(r >> 16);
}
__device__ __forceinline__ float bf2f(unsigned short h) {
    unsigned u = ((unsigned)h) << 16;
    return __builtin_bit_cast(float, u);
}

// 32 blocks x 256: c[k], hist/loss zero, bf16-hi frags.
// chunk = (code>>4)*2 + ks, lane = kg*16 + (code&15); element j <-> d = ks*32+kg*8+j
__global__ __launch_bounds__(256) void vq_prep(const float* __restrict__ W,
                                               float* __restrict__ ws) {
    const int gid = blockIdx.x * 256 + threadIdx.x;   // 0..8191
    {
        const int code = gid >> 3;
        const int seg  = gid & 7;           // ks = seg>>2, kg = seg&3
        const int d0   = seg << 3;
        const float4* wp = (const float4*)(W + (code << 6) + d0);
        const float4 g0 = wp[0], g1 = wp[1];
        const float vv[8] = {g0.x, g0.y, g0.z, g0.w, g1.x, g1.y, g1.z, g1.w};
        S8 hs;
        #pragma unroll
        for (int j = 0; j < 8; ++j) hs.u[j] = f2bf_rne(vv[j]);
        const int chunk = (code >> 4) * 2 + (seg >> 2);
        const int lane  = ((seg & 3) << 4) + (code & 15);
        ((short8*)(ws + FRAG_OFF))[chunk * 64 + lane] = hs.v;
    }
    if (gid < N_EMB_K) {
        const float* wk = W + (gid << 6);
        float s = 0.f;
        #pragma unroll
        for (int d = 0; d < EMB_D; ++d) s = fmaf(wk[d], wk[d], s);
        ws[gid] = 0.5f * s;
        ((unsigned int*)ws)[1024 + gid] = 0u;
        if (gid == 0) ws[2048] = 0.f;
    }
}

// 256 blocks x 512 thr, 1 block/CU (133 KB LDS). Block owns 256 points, 4 rounds.
// Waves 0-3: compute (argmin+quant+loss). Waves 4-7: dedicated enc storers,
// synced via LDS spin-flags (NO s_barrier in the pipeline -> no vmcnt(0) drain;
// storer vmcnt never blocks compute waves).
__global__ __launch_bounds__(512, 2) void vq_main(const float* __restrict__ in,
                                                  const float* __restrict__ W,
                                                  float* __restrict__ out,
                                                  float* __restrict__ ws) {
    __shared__ short8 frag_lds[8192];   // 128 KB bf16-hi codebook
    __shared__ float  c_lds[1024];      // 4 KB
    __shared__ int    s_bk[4][64];      // per-round winners (no reuse -> no WAR)
    __shared__ int    s_flag[4];

    const int tid  = threadIdx.x;
    const int lane = tid & 63;
    const int wv   = tid >> 6;          // 0..7
    const int n16  = lane & 15;
    const int quad = lane >> 4;

    const int blk = blockIdx.x;         // 0..255
    const int b   = blk >> 4;           // image
    const int hwb = (blk & 15) * 256;   // 256 consecutive hw positions

    // ---- stage codebook + c, init flags (before any big stores -> barriers cheap) ----
    {
        const short8* fsrc = (const short8*)(ws + FRAG_OFF);
        #pragma unroll
        for (int i = 0; i < 16; ++i) frag_lds[i * 512 + tid] = fsrc[i * 512 + tid];
        if (tid < 256) ((f4*)c_lds)[tid] = ((const f4*)ws)[tid];
        if (tid < 4) s_flag[tid] = 0;
    }
    __syncthreads();

    if (wv < 4) {
        // ================= COMPUTE WAVES =================
        float qx[16], qxn[16];
        {   // round-0 x: point p = wv*16+n16, d = quad*8+j (+32)
            const float* xp = in + (size_t)b * CHW + hwb + (wv * 16 + n16);
            #pragma unroll
            for (int j = 0; j < 8; ++j) {
                qx[j]     = xp[(quad * 8 + j) * HW];
                qx[j + 8] = xp[(quad * 8 + j + 32) * HW];
            }
        }
        float lsum = 0.f;
        #pragma unroll
        for (int r = 0; r < 4; ++r) {
            short8 ah0, ah1, al0, al1;
            {
                S8 h0, h1, l0, l1;
                #pragma unroll
                for (int j = 0; j < 8; ++j) {
                    h0.u[j] = f2bf_rne(qx[j]);     l0.u[j] = f2bf_rne(qx[j]     - bf2f(h0.u[j]));
                    h1.u[j] = f2bf_rne(qx[j + 8]); l1.u[j] = f2bf_rne(qx[j + 8] - bf2f(h1.u[j]));
                }
                ah0 = h0.v; al0 = l0.v; ah1 = h1.v; al1 = l1.v;
            }
            float bestv[4] = {-3.0e38f, -3.0e38f, -3.0e38f, -3.0e38f};
            int   bestk[4] = {0, 0, 0, 0};
            #pragma unroll 2
            for (int t = 0; t < 64; ++t) {
                const short8 bh0 = frag_lds[(2 * t) * 64 + lane];
                const short8 bh1 = frag_lds[(2 * t + 1) * 64 + lane];
                const float  cv  = c_lds[(t << 4) + n16];
                float4v acc = {-cv, -cv, -cv, -cv};   // score = x.w - 0.5||w||^2
                acc = __builtin_amdgcn_mfma_f32_16x16x32_bf16(ah0, bh0, acc, 0, 0, 0);
                acc = __builtin_amdgcn_mfma_f32_16x16x32_bf16(ah1, bh1, acc, 0, 0, 0);
                acc = __builtin_amdgcn_mfma_f32_16x16x32_bf16(al0, bh0, acc, 0, 0, 0);
                acc = __builtin_amdgcn_mfma_f32_16x16x32_bf16(al1, bh1, acc, 0, 0, 0);
                const int code = (t << 4) + n16;
                #pragma unroll
                for (int rr = 0; rr < 4; ++rr) {
                    if (acc[rr] > bestv[rr]) { bestv[rr] = acc[rr]; bestk[rr] = code; }  // > => lowest k
                }
            }
            #pragma unroll
            for (int off = 1; off < 16; off <<= 1) {
                #pragma unroll
                for (int rr = 0; rr < 4; ++rr) {
                    const float ov = __shfl_xor(bestv[rr], off, 64);
                    const int   oi = __shfl_xor(bestk[rr], off, 64);
                    if (ov > bestv[rr] || (ov == bestv[rr] && oi < bestk[rr])) {
                        bestv[rr] = ov; bestk[rr] = oi;
                    }
                }
            }
            if (n16 == 0) {
                #pragma unroll
                for (int rr = 0; rr < 4; ++rr) s_bk[r][wv * 16 + quad * 4 + rr] = bestk[rr];
            }
            if (lane == 0)
                __hip_atomic_fetch_add(&s_flag[r], 1, __ATOMIC_RELEASE, __HIP_MEMORY_SCOPE_WORKGROUP);

            // prefetch next round's x BEFORE quant stores (loads older than stores
            // in vmcnt order -> x wait never waits on stores)
            if (r < 3) {
                const float* xp = in + (size_t)b * CHW + hwb + ((r + 1) * 64 + wv * 16 + n16);
                #pragma unroll
                for (int j = 0; j < 8; ++j) {
                    qxn[j]     = xp[(quad * 8 + j) * HW];
                    qxn[j + 8] = xp[(quad * 8 + j + 32) * HW];
                }
            }

            // quant + loss for round r (winner row from LDS bf16 frags; no global loads)
            {
                const int p  = r * 64 + wv * 16 + n16;     // block-local point
                const int bk = s_bk[r][wv * 16 + n16];     // same-wave LDS, in-order
                const int ch = (bk >> 4) * 2;
                const int fl = quad * 16 + (bk & 15);
                const S8 w0 = {frag_lds[ch * 64 + fl]};
                const S8 w1 = {frag_lds[(ch + 1) * 64 + fl]};
                float* qbase = out + Q_OFF + (size_t)b * CHW + hwb + p;
                #pragma unroll
                for (int j = 0; j < 8; ++j) {
                    const int d = quad * 8 + j;
                    const float d0 = bf2f(w0.u[j]) - qx[j];
                    const float d1 = bf2f(w1.u[j]) - qx[j + 8];
                    lsum = fmaf(d0, d0, lsum);
                    lsum = fmaf(d1, d1, lsum);
                    qbase[d * HW]        = qx[j] + d0;     // straight-through arithmetic
                    qbase[(d + 32) * HW] = qx[j + 8] + d1;
                }
            }
            if (r < 3) {
                #pragma unroll
                for (int j = 0; j < 16; ++j) qx[j] = qxn[j];
            }
        }
        #pragma unroll
        for (int off = 1; off < 64; off <<= 1) lsum += __shfl_xor(lsum, off, 64);
        if (lane == 0) atomicAdd(ws + 2048, lsum);
    } else {
        // ================= STORER WAVES =================
        const int sw = wv - 4;            // 0..3
        float* encb = out + ENC_OFF;      // byte ≡ 8 mod 16; +2 floats -> 16B aligned
        for (int r = 0; r < 4; ++r) {
            while (__hip_atomic_load(&s_flag[r], __ATOMIC_ACQUIRE, __HIP_MEMORY_SCOPE_WORKGROUP) < 4)
                __builtin_amdgcn_s_sleep(2);
            if (sw == 0)
                atomicAdd((unsigned int*)ws + 1024 + s_bk[r][lane], 1u);   // histogram, 64 pts/round
            #pragma unroll 2
            for (int rr = 0; rr < 16; ++rr) {
                const int l  = sw * 16 + rr;
                const int bk = s_bk[r][l];
                float* row = encb + ((size_t)(blk * 256 + r * 64 + l)) * 1024;
                #pragma unroll
                for (int s = 0; s < 4; ++s) {
                    const int j = 4 * lane + s;           // 0..255
                    if (j < 255) {
                        const int c = 2 + 4 * j;
                        f4 v;
                        v.x = (bk == c)     ? 1.0f : 0.0f;
                        v.y = (bk == c + 1) ? 1.0f : 0.0f;
                        v.z = (bk == c + 2) ? 1.0f : 0.0f;
                        v.w = (bk == c + 3) ? 1.0f : 0.0f;
                        *(f4*)(row + c) = v;
                    }
                }
                if (lane == 63) {
                    f2 v0, v1;
                    v0.x = (bk == 0)    ? 1.0f : 0.0f;
                    v0.y = (bk == 1)    ? 1.0f : 0.0f;
                    v1.x = (bk == 1022) ? 1.0f : 0.0f;
                    v1.y = (bk == 1023) ? 1.0f : 0.0f;
                    *(f2*)(row)        = v0;
                    *(f2*)(row + 1022) = v1;
                }
            }
        }
    }
}

__global__ __launch_bounds__(256) void vq_final(const float* __restrict__ ws,
                                                float* __restrict__ out) {
    __shared__ float red[256];
    const int tid = threadIdx.x;
    const unsigned int* hist = (const unsigned int*)ws + 1024;
    float local = 0.f;
    #pragma unroll
    for (int j = 0; j < 4; ++j) {
        const unsigned int cnt = hist[tid + j * 256];
        const float pr = (float)cnt * (1.0f / 65536.0f);
        local += pr * logf(pr + 1e-10f);
    }
    red[tid] = local;
    __syncthreads();
    for (int off = 128; off > 0; off >>= 1) {
        if (tid < off) red[tid] += red[tid + off];
        __syncthreads();
    }
    if (tid == 0) {
        out[PERP_OFF] = expf(-red[0]);
        out[0] = 1.25f * ws[2048] * (1.0f / 4194304.0f);
    }
}

extern "C" void kernel_launch(void* const* d_in, const int* in_sizes, int n_in,
                              void* d_out, int out_size, void* d_ws, size_t ws_size,
                              hipStream_t stream) {
    const float* in = (const float*)d_in[0];   // (16,64,64,64) fp32 NCHW
    const float* W  = (const float*)d_in[1];   // (1024,64) fp32
    float* out = (float*)d_out;                // [loss | quant(4194304) | perp | enc(67108864)]
    float* ws  = (float*)d_ws;

    vq_prep<<<32, 256, 0, stream>>>(W, ws);
    vq_main<<<256, 512, 0, stream>>>(in, W, out, ws);
    vq_final<<<1, 256, 0, stream>>>(ws, out);
}